// Round 8
// baseline (117.599 us; speedup 1.0000x reference)
//
#include <hip/hip_runtime.h>
#include <math.h>

// Problem constants (fixed by setup_inputs)
#define BSZ    2
#define LFULL  4096
#define MLEN   2048      // M = hidden_states.shape[1]
#define DMODEL 2048
#define CLIP_EPS 1e-4f
#define CCH    256       // number of chunks
#define TCH    8         // chunk length; CCH*TCH == MLEN

typedef float f4 __attribute__((ext_vector_type(4)));

// ---------------------------------------------------------------------------
// MEGA v3: entire layer in ONE dispatch, zero cross-block communication.
//
// v3 change (from R7 counters: 101 MB at ~3 TB/s effective -> 64-B segment
// pattern halves HBM efficiency): each thread owns TWO adjacent f4 columns
// (strip = 32 floats). A 4-lane (j) group's A+B accesses of one row cover
// exactly one 128-B line, so every global load/store moves whole lines.
// grid: (DMODEL/32, BSZ) = (64, 2) = 128 blocks x 1024 threads
//       (256 chunks x 4 j-lanes; 2048 waves -> HBM saturated).
// LDS: sel 8KB + scan S [256][9] f4 36.9KB (36-dword row stride -> 2-way
//      bank aliasing = free) + P 1KB ~= 46 KB.
// LB(1024,4): 16 waves/CU, VGPR cap 128; pinned xr(64)+prep(~30) fits ->
// hid loads stay hoisted above the prep phase (R6 pathology avoided).
// All arithmetic bit-identical to the verified pipeline.
// ---------------------------------------------------------------------------
__global__ __launch_bounds__(1024, 4) void mega(
    const float* __restrict__ hid, const int* __restrict__ bmask_raw,
    const float* __restrict__ bprob, float* __restrict__ out)
{
  const int tid = threadIdx.x;
  const int j   = tid & 3;          // j-lane within the 32-float strip
  const int c   = tid >> 2;         // chunk [0, 256)
  const int bx  = blockIdx.x;       // strip [0, 64)
  const int b   = blockIdx.y;       // batch

  __shared__ int   s_sel[MLEN];     // 8 KB, alive through the epilogue
  __shared__ float s_P[CCH];        // 1 KB
  __shared__ f4    s_S[CCH][9];     // 36.9 KB ([c][2j]=A, [2j+1]=B; pad col 8)
  __shared__ int   s_wtot[16];      // per-wave counts -> exclusive offsets
  __shared__ int   s_mode, s_ntrue;

  // ---- phase A: issue this block's hid loads; keep-alive pins them ----
  const int d4 = bx * 8 + 2 * j;    // f4 column index [0, 512), owns d4, d4+1
  const int o  = b * MLEN + c * TCH;
  const f4* xp = (const f4*)hid + ((size_t)o * DMODEL >> 2) + d4;
  f4 xrA[TCH], xrB[TCH];
  #pragma unroll
  for (int t = 0; t < TCH; ++t) {
    xrA[t] = xp[(size_t)t * (DMODEL / 4)];
    xrB[t] = xp[(size_t)t * (DMODEL / 4) + 1];
  }
  #pragma unroll
  for (int t = 0; t < TCH; ++t) {
    asm volatile("" : "+v"(xrA[t]));
    asm volatile("" : "+v"(xrB[t]));
  }

  // ---- phase B: redundant prep, all 1024 threads (4 positions each) ----
  if (tid == 0) {
    unsigned w0 = ((const unsigned*)bmask_raw)[0];
    s_mode = (w0 <= 1u) ? 1 : 0;    // 1: int32 per element, 0: uint8
  }
  __syncthreads();
  const int mode = s_mode;
  const unsigned char* bmask_u8 = (const unsigned char*)bmask_raw;

  const int PER  = LFULL / 1024;    // 4 positions per thread
  const int base = tid * PER;

  int cnt = 0;
  {
    #pragma unroll
    for (int i = 0; i < PER; ++i) {
      const int L = base + i;
      const int v = mode ? (bmask_raw[b * LFULL + L] != 0)
                         : (bmask_u8[b * LFULL + L] != 0);
      cnt += v;
    }
  }

  // two-level exclusive prefix over 1024 per-thread counts
  const int lane = tid & 63, wv = tid >> 6;
  int incl = cnt;
  #pragma unroll
  for (int off = 1; off < 64; off <<= 1) {
    const int v = __shfl_up(incl, off, 64);
    if (lane >= off) incl += v;
  }
  if (lane == 63) s_wtot[wv] = incl;     // wave totals
  __syncthreads();
  if (tid == 0) {
    int run = 0;
    #pragma unroll
    for (int w = 0; w < 16; ++w) { const int t = s_wtot[w]; s_wtot[w] = run; run += t; }
    s_ntrue = run;
  }
  __syncthreads();
  const int excl  = (incl - cnt) + s_wtot[wv];
  const int ntrue = s_ntrue;

  // fill sel: boundary positions (rank) then non-boundary (ntrue + false-rank)
  {
    int trun = excl;
    #pragma unroll
    for (int i = 0; i < PER; ++i) {
      const int L = base + i;
      const int v = mode ? (bmask_raw[b * LFULL + L] != 0)
                         : (bmask_u8[b * LFULL + L] != 0);
      if (v) {
        if (trun < MLEN) s_sel[trun] = L;
        ++trun;
      } else {
        const int f = L - trun;          // falses strictly before L
        const int slot = ntrue + f;
        if (slot < MLEN) s_sel[slot] = L;
      }
    }
  }
  __syncthreads();

  // own-chunk params to registers (4 j-lanes compute redundantly);
  // bit-identical formulas: w = p/dt, e = 1-p, cde = running product.
  float w[TCH], e[TCH], cd[TCH];
  {
    float run = 1.0f;
    #pragma unroll
    for (int t = 0; t < TCH; ++t) {
      const int L = s_sel[c * TCH + t];
      float p = bprob[((size_t)b * LFULL + L) * 2 + 1];
      p = fminf(fmaxf(p, CLIP_EPS), 1.0f - CLIP_EPS);
      const float dt = -log1pf(-p);      // log(1/(1-p))
      w[t] = p / dt;
      e[t] = 1.0f - p;                   // exp(-dt) exactly
      run *= e[t];
      cd[t] = run;
    }
  }

  // ---- phase C: local chunk scan in registers; publish S, P ----
  f4 stA = {0.f, 0.f, 0.f, 0.f};
  f4 stB = {0.f, 0.f, 0.f, 0.f};
  #pragma unroll
  for (int t = 0; t < TCH; ++t) {
    const f4 xA = xrA[t], xB = xrB[t];
    stA.x = fmaf(e[t], stA.x, w[t] * xA.x);
    stA.y = fmaf(e[t], stA.y, w[t] * xA.y);
    stA.z = fmaf(e[t], stA.z, w[t] * xA.z);
    stA.w = fmaf(e[t], stA.w, w[t] * xA.w);
    stB.x = fmaf(e[t], stB.x, w[t] * xB.x);
    stB.y = fmaf(e[t], stB.y, w[t] * xB.y);
    stB.z = fmaf(e[t], stB.z, w[t] * xB.z);
    stB.w = fmaf(e[t], stB.w, w[t] * xB.w);
    xrA[t] = stA;                        // running local state at position t
    xrB[t] = stB;
  }
  s_S[c][2 * j]     = stA;
  s_S[c][2 * j + 1] = stB;
  if (j == 0) s_P[c] = cd[TCH - 1];      // chunk product
  __syncthreads();

  // ---- phase D: Hillis-Steele over 256 chunks (identical to k25 math) ----
  for (int dstep = 1; dstep < CCH; dstep <<= 1) {
    const float pc = s_P[c];
    float pd = 1.0f;
    f4 sdA = {0.f, 0.f, 0.f, 0.f};
    f4 sdB = {0.f, 0.f, 0.f, 0.f};
    if (c >= dstep) {
      pd  = s_P[c - dstep];
      sdA = s_S[c - dstep][2 * j];
      sdB = s_S[c - dstep][2 * j + 1];
    }
    __syncthreads();
    if (c >= dstep) {
      f4 curA = s_S[c][2 * j];
      f4 curB = s_S[c][2 * j + 1];
      curA.x = fmaf(pc, sdA.x, curA.x);
      curA.y = fmaf(pc, sdA.y, curA.y);
      curA.z = fmaf(pc, sdA.z, curA.z);
      curA.w = fmaf(pc, sdA.w, curA.w);
      curB.x = fmaf(pc, sdB.x, curB.x);
      curB.y = fmaf(pc, sdB.y, curB.y);
      curB.z = fmaf(pc, sdB.z, curB.z);
      curB.w = fmaf(pc, sdB.w, curB.w);
      s_S[c][2 * j]     = curA;
      s_S[c][2 * j + 1] = curB;
      if (j == 0) s_P[c] = pc * pd;
    }
    __syncthreads();
  }

  // exclusive shift: carry-in for chunk c is inclusive scan at c-1
  f4 HA = {0.f, 0.f, 0.f, 0.f};
  f4 HB = {0.f, 0.f, 0.f, 0.f};
  if (c > 0) { HA = s_S[c - 1][2 * j]; HB = s_S[c - 1][2 * j + 1]; }

  // ---- phase E: y = xr + cde*H, NT scatter to rows [ls, le) from s_sel ----
  const int nb = (ntrue < MLEN) ? ntrue : MLEN;
  f4* op = (f4*)out + ((size_t)b * LFULL * DMODEL >> 2) + d4;
  #pragma unroll
  for (int t = 0; t < TCH; ++t) {
    const int g = c * TCH + t;           // global selected index [0, MLEN)
    int ls, le;
    if (nb == 0) {
      ls = (g == 0) ? 0 : LFULL;
      le = (g == 0) ? LFULL : LFULL;
    } else if (g < nb) {
      ls = (g == 0) ? 0 : s_sel[g];
      le = (g == nb - 1) ? LFULL : s_sel[g + 1];
    } else {
      ls = LFULL; le = LFULL;            // empty
    }
    f4 yA, yB;
    yA.x = fmaf(cd[t], HA.x, xrA[t].x);
    yA.y = fmaf(cd[t], HA.y, xrA[t].y);
    yA.z = fmaf(cd[t], HA.z, xrA[t].z);
    yA.w = fmaf(cd[t], HA.w, xrA[t].w);
    yB.x = fmaf(cd[t], HB.x, xrB[t].x);
    yB.y = fmaf(cd[t], HB.y, xrB[t].y);
    yB.z = fmaf(cd[t], HB.z, xrB[t].z);
    yB.w = fmaf(cd[t], HB.w, xrB[t].w);
    for (int L = ls; L < le; ++L) {
      f4* row = op + (size_t)L * (DMODEL / 4);
      __builtin_nontemporal_store(yA, row);
      __builtin_nontemporal_store(yB, row + 1);
    }
  }
}

// ---------------------------------------------------------------------------
extern "C" void kernel_launch(void* const* d_in, const int* in_sizes, int n_in,
                              void* d_out, int out_size, void* d_ws, size_t ws_size,
                              hipStream_t stream) {
  const float* hid   = (const float*)d_in[0];   // (2, 2048, 2048) fp32
  const int*   bmask = (const int*)d_in[1];     // (2, 4096) bool (layout sniffed)
  const float* bprob = (const float*)d_in[2];   // (2, 4096, 2) fp32
  float*       out   = (float*)d_out;           // (2, 4096, 2048) fp32
  (void)d_ws; (void)ws_size;

  mega<<<dim3(DMODEL / 32, BSZ), dim3(1024), 0, stream>>>(hid, bmask, bprob, out);
}